// Round 4
// baseline (136.166 us; speedup 1.0000x reference)
//
#include <hip/hip_runtime.h>

// CompletePatchReadout: grouped GEMM (128 patches, M=32 K=1536 N=768) + bias + row scatter.
// Memory-bound on W (604 MB fp32, read once). bf16 MFMA, W direct-to-register, 2-deep
// register pipeline. x staged in LDS bf16 in two half-K chunks -> only 3 barriers/block
// (vs 24), so W loads never drain at barriers (the round-2 ~25% stall).
// Round-3 bug fixed: (k0 & (KH-1)) with KH=768 non-pow2 -> (k0 >= KH ? k0-KH : k0).

constexpr int T      = 12;
constexpr int P      = 128;
constexpr int F      = 128;
constexpr int K      = T * F;        // 1536
constexpr int N      = 768;          // 64 nodes * 12 horizon
constexpr int NPP    = 64;
constexpr int H      = 12;
constexpr int NNODES = P * NPP;      // 8192
constexpr int BN     = 128;          // N-tile per block
constexpr int NT     = N / BN;       // 6
constexpr int KH     = 768;          // K per LDS half (NOT a power of two!)
constexpr int TPF    = T * P * F;
constexpr int PF     = P * F;

typedef __attribute__((ext_vector_type(8))) short  bf16x8;
typedef __attribute__((ext_vector_type(4))) float  f32x4;

__device__ inline short f2bf(float f) {            // fp32 -> bf16 RNE
    unsigned u = __float_as_uint(f);
    u += 0x7fffu + ((u >> 16) & 1u);
    return (short)(u >> 16);
}

__global__ __launch_bounds__(256, 3)
void patch_readout_kernel(const float* __restrict__ x,
                          const float* __restrict__ W,
                          const float* __restrict__ bias,
                          const int*   __restrict__ map,
                          float*       __restrict__ out)
{
    // x half-tile: 32 rows x 768 k, bf16, XOR-swizzled 16B slots. 48 KB -> 3 blocks/CU.
    __shared__ short As[32 * KH];
    char* lds = (char*)&As[0];

    const int p    = blockIdx.y;
    const int n0   = blockIdx.x * BN;
    const int tid  = threadIdx.x;
    const int lane = tid & 63;
    const int wv   = tid >> 6;        // wave -> 32-col slice
    const int r    = lane & 15;
    const int c    = lane >> 4;       // k-octet within 32-chunk

    // W fragment base: lane (c,r), wave wv: col = n0+wv*32+ni*16+r, k = k0+kc*32+8c+j
    const float* wb = W + (size_t)p * K * N + (size_t)(8 * c) * N + (n0 + wv * 32 + r);

    f32x4 acc[2][2] = {};             // [mi][ni]

    auto issueW = [&](int k0, float* wd) {
        #pragma unroll
        for (int kc = 0; kc < 2; ++kc)
            #pragma unroll
            for (int ni = 0; ni < 2; ++ni)
                #pragma unroll
                for (int j = 0; j < 8; ++j)
                    wd[kc * 16 + ni * 8 + j] = wb[(size_t)(k0 + kc * 32 + j) * N + ni * 16];
    };

    auto computeStep = [&](int k0, const float* wd) {
        bf16x8 bfr[2][2];             // [kc][ni]
        #pragma unroll
        for (int kc = 0; kc < 2; ++kc)
            #pragma unroll
            for (int ni = 0; ni < 2; ++ni)
                #pragma unroll
                for (int j = 0; j < 8; ++j)
                    bfr[kc][ni][j] = f2bf(wd[kc * 16 + ni * 8 + j]);

        // byte col within half; KH is NOT pow2, so no mask trick
        const int kl = (k0 >= KH) ? (k0 - KH) : k0;
        const int kb = kl * 2;
        bf16x8 afr[2][2];             // [mi][kc]
        #pragma unroll
        for (int mi = 0; mi < 2; ++mi)
            #pragma unroll
            for (int kc = 0; kc < 2; ++kc) {
                int row  = mi * 16 + r;
                int byte = row * (KH * 2) + ((kb + kc * 64 + c * 16) ^ ((row & 7) << 4));
                afr[mi][kc] = *(const bf16x8*)(lds + byte);
            }

        #pragma unroll
        for (int mi = 0; mi < 2; ++mi)
            #pragma unroll
            for (int ni = 0; ni < 2; ++ni)
                #pragma unroll
                for (int kc = 0; kc < 2; ++kc)
                    acc[mi][ni] = __builtin_amdgcn_mfma_f32_16x16x32_bf16(
                        afr[mi][kc], bfr[kc][ni], acc[mi][ni], 0, 0, 0);
    };

    auto stageX = [&](int half) {
        const int row = tid >> 3;
        const int sub = tid & 7;
        const float* xr = x + (size_t)row * TPF + (size_t)p * F;
        #pragma unroll
        for (int ci = 0; ci < 12; ++ci) {
            int k  = ci * 64 + sub * 8;           // k within half
            int kg = half * KH + k;               // global k
            int ti = kg >> 7;                     // t index (F==128)
            int f  = kg & 127;
            const f32x4* sp = (const f32x4*)(xr + (size_t)ti * PF + f);
            f32x4 v0 = sp[0];
            f32x4 v1 = sp[1];
            bf16x8 av;
            av[0] = f2bf(v0.x); av[1] = f2bf(v0.y); av[2] = f2bf(v0.z); av[3] = f2bf(v0.w);
            av[4] = f2bf(v1.x); av[5] = f2bf(v1.y); av[6] = f2bf(v1.z); av[7] = f2bf(v1.w);
            *(bf16x8*)(lds + row * (KH * 2) + ((k * 2) ^ ((row & 7) << 4))) = av;
        }
    };

    float wA[32], wB[32];             // 2-deep W register pipeline (named: rule #20)

    stageX(0);
    issueW(0, wA);
    __syncthreads();                  // barrier 1: half-0 visible

    for (int ds = 0; ds < 12; ++ds) {
        if (ds == 6) {
            __syncthreads();          // barrier 2: all waves done reading half 0
            stageX(1);
            __syncthreads();          // barrier 3: half-1 visible
        }
        const int s0 = ds * 2;
        issueW((s0 + 1) * 64, wB);
        computeStep(s0 * 64, wA);
        if (ds < 11) issueW((s0 + 2) * 64, wA);
        computeStep((s0 + 1) * 64, wB);
    }

    // ---- epilogue: bias + permutation scatter ----
    #pragma unroll
    for (int ni = 0; ni < 2; ++ni) {
        const int col = n0 + wv * 32 + ni * 16 + r;   // output col in [0,768)
        const int nl  = col / H;                      // patch-local node
        const int h   = col - nl * H;                 // horizon
        const int g   = map[p * NPP + nl];            // global node
        const float bv = bias[p * N + col];
        #pragma unroll
        for (int mi = 0; mi < 2; ++mi) {
            #pragma unroll
            for (int i = 0; i < 4; ++i) {
                const int b = mi * 16 + c * 4 + i;    // batch row (C/D layout verified)
                out[((size_t)b * NNODES + g) * H + h] = acc[mi][ni][i] + bv;
            }
        }
    }
}

extern "C" void kernel_launch(void* const* d_in, const int* in_sizes, int n_in,
                              void* d_out, int out_size, void* d_ws, size_t ws_size,
                              hipStream_t stream) {
    const float* x    = (const float*)d_in[0];
    const float* W    = (const float*)d_in[1];
    const float* bias = (const float*)d_in[2];
    const int*   map  = (const int*)d_in[3];
    float*       out  = (float*)d_out;

    dim3 grid(NT, P);   // (6, 128) = 768 blocks, 3/CU
    dim3 block(256);
    patch_readout_kernel<<<grid, block, 0, stream>>>(x, W, bias, map, out);
}